// Round 6
// baseline (672.828 us; speedup 1.0000x reference)
//
#include <hip/hip_runtime.h>
#include <hip/hip_bf16.h>

// x [N=32, C=64, H=128, W=128] fp32; two 3x3 convs (stride1 pad1) + train-mode BN + residual.
#define NB 32
#define CH 64
#define HH 128
#define WW 128
#define HW (HH*WW)          // 16384
#define CHW (CH*HW)         // 1048576
#define NCHW (NB*CHW)       // 33554432
#define CNT_PER_CH ((float)(NB*HW))
#define ROWS 4              // rows per conv block
#define NBLK 1024           // conv grid

typedef __attribute__((ext_vector_type(8)))  short short8;
typedef __attribute__((ext_vector_type(16))) float f32x16;

__device__ __forceinline__ unsigned short f2bf(float f) {
  unsigned u = __builtin_bit_cast(unsigned, f);
  u += 0x7fffu + ((u >> 16) & 1u);          // round-to-nearest-even
  return (unsigned short)(u >> 16);
}

__device__ __forceinline__ void gld_lds16(const void* g, void* s) {
  __builtin_amdgcn_global_load_lds(
      (const __attribute__((address_space(1))) unsigned int*)g,
      (__attribute__((address_space(3))) unsigned int*)s, 16, 0, 0);
}

// ---------------------------------------------------------------------------
// T1: x NCHW fp32 -> blocked NHWC bf16: xb[n][h][cb=ci/8][w][ci%8]
__global__ __launch_bounds__(256) void t1_pack(const float* __restrict__ x,
                                               unsigned short* __restrict__ xb) {
  __shared__ __align__(16) unsigned short tmp[CH * WW];   // [ci][w] 16KB
  const int bid = blockIdx.x;                 // n*128 + h
  const int tid = threadIdx.x;
  const float* src = x + (size_t)(bid >> 7) * CHW + (size_t)(bid & 127) * WW;
  for (int i = tid; i < 2048; i += 256) {     // 64 ci * 32 float4
    const int ci = i >> 5, wq = i & 31;
    const float4 v = *(const float4*)(src + (size_t)ci * HW + wq * 4);
    unsigned short* d = &tmp[ci * WW + wq * 4];
    d[0] = f2bf(v.x); d[1] = f2bf(v.y); d[2] = f2bf(v.z); d[3] = f2bf(v.w);
  }
  __syncthreads();
  unsigned short* dst = xb + (size_t)bid * 8192;          // 8 cb * 128 w * 8
  for (int i = tid; i < 1024; i += 256) {     // chunks (cb,w)
    const int cb = i >> 7, w = i & 127;
    const unsigned short* s = &tmp[cb * 8 * WW + w];
    uint4 o;
    o.x = (unsigned)s[0]      | ((unsigned)s[WW]     << 16);
    o.y = (unsigned)s[2*WW]   | ((unsigned)s[3*WW]   << 16);
    o.z = (unsigned)s[4*WW]   | ((unsigned)s[5*WW]   << 16);
    o.w = (unsigned)s[6*WW]   | ((unsigned)s[7*WW]   << 16);
    *(uint4*)(dst + ((size_t)cb * WW + w) * 8) = o;
  }
}

// ---------------------------------------------------------------------------
// Weight prepack into MFMA A-fragment order (M=co, K=ci per tap).
// frag f = ((kh*3+kw)*4 + kq)*2 + m ; element [f][lane][r] =
//   w[co=(lane&31)+32m][ci=kq*16+(lane>>5)*8+r][kh][kw]  (* s1[ci] if folding)
// Also emits BN1-bias border tables for conv2 (tabs[9][64]).
__global__ __launch_bounds__(256) void pack_w(const float* __restrict__ w,
                                              const float* __restrict__ s1,
                                              const float* __restrict__ b1,
                                              unsigned short* __restrict__ wpk,
                                              float* __restrict__ tabs) {
  const int tid = threadIdx.x;
  for (int idx = tid; idx < 36864; idx += 256) {
    const int f = idx >> 9, l = (idx >> 3) & 63, r = idx & 7;
    const int m = f & 1, kq = (f >> 1) & 3, t = f >> 3;   // t = kh*3+kw
    const int co = (l & 31) + 32 * m;
    const int ci = kq * 16 + (l >> 5) * 8 + r;
    float v = w[co * 576 + ci * 9 + t];
    if (s1) v *= s1[ci];
    wpk[idx] = f2bf(v);
  }
  if (tabs != nullptr && tid < 64) {
    const int co = tid;
    float tb[9];
    for (int t = 0; t < 9; ++t) {
      float a = 0.f;
      for (int ci = 0; ci < 64; ++ci) a += w[co * 576 + ci * 9 + t] * b1[ci];
      tb[t] = a;
    }
    tabs[0*64+co] = tb[0]+tb[1]+tb[2]+tb[3]+tb[4]+tb[5]+tb[6]+tb[7]+tb[8];
    tabs[1*64+co] = tb[0]+tb[1]+tb[2];   // kh=0 row
    tabs[2*64+co] = tb[6]+tb[7]+tb[8];   // kh=2 row
    tabs[3*64+co] = tb[0]+tb[3]+tb[6];   // kw=0 col
    tabs[4*64+co] = tb[2]+tb[5]+tb[8];   // kw=2 col
    tabs[5*64+co] = tb[0]; tabs[6*64+co] = tb[2];
    tabs[7*64+co] = tb[6]; tabs[8*64+co] = tb[8];
  }
}

// ---------------------------------------------------------------------------
// MFMA conv v6: identical to v5 EXCEPT register pressure:
//  - __launch_bounds__(256, 1): VGPR cap 512 -> wr[36] (144 VGPR) stays
//    resident, NO spill/remat (v5 allocated 128 < 144 live -> spilled).
//  - residual read inline in epilogue (rv prefetch removed, -32 VGPR).
template <bool IS2>
__global__ __launch_bounds__(256, 1)
void conv_mfma(const unsigned short* __restrict__ inb,
               const unsigned short* __restrict__ wpack,
               const float* __restrict__ tabs,
               const float* __restrict__ resid,       // x fp32 NCHW (IS2)
               unsigned short* __restrict__ outb,     // conv1 out (blocked bf16)
               float* __restrict__ outf,              // conv2 out (NCHW fp32)
               float* __restrict__ pblk_s, float* __restrict__ pblk_q) {
  extern __shared__ __align__(16) unsigned short A[];  // [4][8][130][8]
  const int tid = threadIdx.x, bid = blockIdx.x;
  const int n = bid >> 5, h0 = (bid & 31) << 2;
  const int wv = tid >> 6, lane = tid & 63;
  const int half = lane >> 5, lp = lane & 31;
  const int m  = wv & 1;
  const int nb = (wv >> 1) << 1;   // first ntile: 0 or 2

  // stage one input row ir into ring slot (ir+4)&3 (zero-fill if outside image)
  auto stage = [&](int ir) {
    const int sl = (ir + 4) & 3;
#pragma unroll
    for (int t = 0; t < 4; ++t) {
      const int id = wv + 4 * t;          // 16 tasks: (cb, w-half)
      const int cb = id >> 1, wh = id & 1;
      unsigned short* dst = &A[(((sl * 8 + cb) * 130) + 1 + wh * 64) * 8];
      if ((unsigned)ir < 128u) {
        const unsigned short* g = inb + ((((size_t)n * 128 + ir) * 8 + cb) << 10)
                                      + (size_t)(wh * 64 + lane) * 8;
        gld_lds16(g, dst);
      } else {
        *(uint4*)(dst + (size_t)lane * 8) = make_uint4(0, 0, 0, 0);
      }
    }
  };

  // zero the w-halo slots (0 and 129) for all 4 ring slots, once
  if (tid < 64) {
    const int sl = tid >> 4, cb = (tid >> 1) & 7, s = (tid & 1) ? 129 : 0;
    *(uint4*)&A[(((sl * 8 + cb) * 130) + s) * 8] = make_uint4(0, 0, 0, 0);
  }

  // weights into VGPRs (this wave's m-half) -- MUST stay resident (144 VGPR)
  short8 wr[36];
#pragma unroll
  for (int i = 0; i < 36; ++i) {
    const int f = ((i >> 2) << 3) + ((i & 3) << 1) + m;   // t*8 + kq*2 + m
    wr[i] = *(const short8*)(wpack + (size_t)f * 512 + (size_t)lane * 8);
  }

  // running per-thread stats (accumulated over rows & n-tiles)
  float ss[16], qq[16];
#pragma unroll
  for (int i = 0; i < 16; ++i) { ss[i] = 0.f; qq[i] = 0.f; }

  // prologue staging
  stage(h0 - 1); stage(h0); stage(h0 + 1);

  for (int k = 0; k < ROWS; ++k) {
    const int r = h0 + k;
    __syncthreads();          // drains stage(r+1); readers of slot (r+2)&3 done

    if (k < ROWS - 1) stage(r + 2);   // lands during this row's compute

    // ---- 3x3x4 taps, 2 n-tiles ----
    const int sl_m1 = (r + 3) & 3, sl_0 = (r + 4) & 3, sl_p1 = (r + 5) & 3;
    const int slot[3] = {sl_m1, sl_0, sl_p1};
    f32x16 acc0 = {}; f32x16 acc1 = {};
#pragma unroll
    for (int kh = 0; kh < 3; ++kh) {
      const int sb = slot[kh] * 8;
#pragma unroll
      for (int kw = 0; kw < 3; ++kw) {
#pragma unroll
        for (int kq = 0; kq < 4; ++kq) {
          const short8 wf = wr[(kh * 3 + kw) * 4 + kq];
          const int cb = kq * 2 + half;
          const unsigned short* base = &A[((sb + cb) * 130) * 8];
          const short8 b0 = *(const short8*)&base[(nb * 32 + lp + kw) * 8];
          const short8 b1 = *(const short8*)&base[((nb + 1) * 32 + lp + kw) * 8];
          acc0 = __builtin_amdgcn_mfma_f32_32x32x16_bf16(wf, b0, acc0, 0, 0, 0);
          acc1 = __builtin_amdgcn_mfma_f32_32x32x16_bf16(wf, b1, acc1, 0, 0, 0);
        }
      }
    }

    // ---- epilogue ----
    if (!IS2) {
      unsigned short* dst = outb + (((size_t)n * 128 + r) << 13);
#pragma unroll
      for (int nt = 0; nt < 2; ++nt) {
        const f32x16& a = nt ? acc1 : acc0;
        const int px = (nb + nt) * 32 + lp;
#pragma unroll
        for (int rq = 0; rq < 4; ++rq) {
          uint2 pk;
          pk.x = (unsigned)f2bf(a[rq*4+0]) | ((unsigned)f2bf(a[rq*4+1]) << 16);
          pk.y = (unsigned)f2bf(a[rq*4+2]) | ((unsigned)f2bf(a[rq*4+3]) << 16);
          *(uint2*)(dst + (((size_t)(rq + 4*m)) << 10) + (size_t)px * 8 + half * 4) = pk;
        }
      }
    } else {
      const bool bh0 = (r == 0), bh1 = (r == 127);
#pragma unroll
      for (int nt = 0; nt < 2; ++nt) {
        f32x16& a = nt ? acc1 : acc0;
        const int px = (nb + nt) * 32 + lp;
        const bool bw0 = (px == 0), bw1 = (px == 127);
#pragma unroll
        for (int rr = 0; rr < 16; ++rr) {
          const int co = (rr & 3) + ((rr >> 2) << 3) + 4 * half + 32 * m;
          float tb = tabs[co];
          if (bh0) tb -= tabs[64 + co];
          if (bh1) tb -= tabs[128 + co];
          if (bw0) tb -= tabs[192 + co];
          if (bw1) tb -= tabs[256 + co];
          if (bh0 && bw0) tb += tabs[320 + co];
          if (bh0 && bw1) tb += tabs[384 + co];
          if (bh1 && bw0) tb += tabs[448 + co];
          if (bh1 && bw1) tb += tabs[512 + co];
          const size_t oi = (((size_t)n * 64 + co) * 128 + r) * 128 + px;
          const float v = a[rr] + tb + resid[oi];
          outf[oi] = v;
          a[rr] = v;
        }
      }
    }

    // ---- accumulate stats in registers (no cross-lane work here) ----
#pragma unroll
    for (int rr = 0; rr < 16; ++rr) {
      ss[rr] += acc0[rr] + acc1[rr];
      qq[rr] += acc0[rr] * acc0[rr] + acc1[rr] * acc1[rr];
    }
  }

  // ---- block-level stats: shuffle tree + LDS transpose + plain stores ----
  __syncthreads();                        // all waves done reading A
  float* SLs = (float*)A;                 // [2][64]
  float* SLq = SLs + 128;                 // [2][64]
  const int p = wv >> 1;
#pragma unroll
  for (int rr = 0; rr < 16; ++rr) {
    float s = ss[rr], q = qq[rr];
    s += __shfl_xor(s, 1);  q += __shfl_xor(q, 1);
    s += __shfl_xor(s, 2);  q += __shfl_xor(q, 2);
    s += __shfl_xor(s, 4);  q += __shfl_xor(q, 4);
    s += __shfl_xor(s, 8);  q += __shfl_xor(q, 8);
    s += __shfl_xor(s, 16); q += __shfl_xor(q, 16);
    if (lp == 0) {
      const int co = (rr & 3) + ((rr >> 2) << 3) + 4 * half + 32 * m;
      SLs[p * 64 + co] = s;
      SLq[p * 64 + co] = q;
    }
  }
  __syncthreads();
  if (tid < 64) {
    pblk_s[(size_t)bid * 64 + tid] = SLs[tid] + SLs[64 + tid];
  } else if (tid < 128) {
    const int co = tid - 64;
    pblk_q[(size_t)bid * 64 + co] = SLq[co] + SLq[64 + co];
  }
}

// ---------------------------------------------------------------------------
// Reduce NBLK per-block partials -> fused scale/bias.
__global__ __launch_bounds__(256)
void finalize_bn(const float* __restrict__ pblk_s, const float* __restrict__ pblk_q,
                 const float* __restrict__ gamma, const float* __restrict__ beta,
                 float* __restrict__ scale, float* __restrict__ bias) {
  __shared__ float ls[4][64], lq[4][64];
  const int c = threadIdx.x & 63, seg = threadIdx.x >> 6;
  float s = 0.f, q = 0.f;
  for (int i = seg * (NBLK / 4); i < (seg + 1) * (NBLK / 4); ++i) {
    s += pblk_s[(size_t)i * 64 + c];
    q += pblk_q[(size_t)i * 64 + c];
  }
  ls[seg][c] = s; lq[seg][c] = q;
  __syncthreads();
  if (threadIdx.x < 64) {
    s = ls[0][c] + ls[1][c] + ls[2][c] + ls[3][c];
    q = lq[0][c] + lq[1][c] + lq[2][c] + lq[3][c];
    const float mean = s * (1.0f / CNT_PER_CH);
    const float var  = q * (1.0f / CNT_PER_CH) - mean * mean;
    const float inv  = rsqrtf(var + 1e-5f);
    const float sc   = inv * gamma[c];
    scale[c] = sc;
    bias[c]  = beta[c] - mean * sc;
  }
}

// In-place BN2 apply on d_out, float4-vectorized.
__global__ __launch_bounds__(256)
void apply_bn_k(float* __restrict__ out,
                const float* __restrict__ scale, const float* __restrict__ bias) {
  __shared__ float sc[CH], bs[CH];
  if (threadIdx.x < CH) { sc[threadIdx.x] = scale[threadIdx.x]; bs[threadIdx.x] = bias[threadIdx.x]; }
  __syncthreads();
  const size_t total4 = NCHW / 4;
  for (size_t i = (size_t)blockIdx.x * blockDim.x + threadIdx.x; i < total4;
       i += (size_t)gridDim.x * blockDim.x) {
    float4 v = reinterpret_cast<float4*>(out)[i];
    const int c = (int)(((i * 4) >> 14) & 63);
    const float s = sc[c], b = bs[c];
    v.x = fmaf(v.x, s, b);
    v.y = fmaf(v.y, s, b);
    v.z = fmaf(v.z, s, b);
    v.w = fmaf(v.w, s, b);
    reinterpret_cast<float4*>(out)[i] = v;
  }
}

// ---------------------------------------------------------------------------
extern "C" void kernel_launch(void* const* d_in, const int* in_sizes, int n_in,
                              void* d_out, int out_size, void* d_ws, size_t ws_size,
                              hipStream_t stream) {
  const float* x  = (const float*)d_in[0];
  const float* w1 = (const float*)d_in[1];
  const float* w2 = (const float*)d_in[2];
  const float* g1 = (const float*)d_in[3];
  const float* b1 = (const float*)d_in[4];
  const float* g2 = (const float*)d_in[5];
  const float* b2 = (const float*)d_in[6];
  float* out = (float*)d_out;
  char* ws = (char*)d_ws;

  // ws: [XB bf16 64MiB][Y1B bf16 64MiB]
  unsigned short* XB  = (unsigned short*)ws;
  unsigned short* Y1B = (unsigned short*)(ws + 67108864);
  // overlays in XB region (XB dead after conv1):
  unsigned short* W2P = (unsigned short*)ws;          // 73728 B
  float* TABS = (float*)(ws + 73728);                 // 2304 B
  float* SC1  = (float*)(ws + 76032);
  float* BS1  = (float*)(ws + 76288);
  float* SC2  = (float*)(ws + 76544);
  float* BS2  = (float*)(ws + 76800);
  float* P2S  = (float*)(ws + 131072);                // 256 KB (NBLK*64 f32)
  float* P2Q  = (float*)(ws + 131072 + 262144);       // 256 KB
  // overlays in d_out (free until conv2 writes it):
  char* ob = (char*)d_out;
  unsigned short* W1P = (unsigned short*)ob;          // 73728 B
  float* P1S = (float*)(ob + 73728);                  // 256 KB
  float* P1Q = (float*)(ob + 73728 + 262144);         // 256 KB

  const size_t conv_lds = 4 * 8 * 130 * 8 * sizeof(unsigned short);  // 66560

  pack_w<<<1, 256, 0, stream>>>(w1, nullptr, nullptr, W1P, nullptr);
  t1_pack<<<4096, 256, 0, stream>>>(x, XB);
  conv_mfma<false><<<NBLK, 256, conv_lds, stream>>>(XB, W1P, nullptr, nullptr,
                                                    Y1B, nullptr, P1S, P1Q);
  finalize_bn<<<1, 256, 0, stream>>>(P1S, P1Q, g1, b1, SC1, BS1);
  pack_w<<<1, 256, 0, stream>>>(w2, SC1, BS1, W2P, TABS);
  conv_mfma<true><<<NBLK, 256, conv_lds, stream>>>(Y1B, W2P, TABS, x,
                                                   nullptr, out, P2S, P2Q);
  finalize_bn<<<1, 256, 0, stream>>>(P2S, P2Q, g2, b2, SC2, BS2);
  apply_bn_k<<<2048, 256, 0, stream>>>(out, SC2, BS2);
}

// Round 7
// 550.863 us; speedup vs baseline: 1.2214x; 1.2214x over previous
//
#include <hip/hip_runtime.h>
#include <hip/hip_bf16.h>

// x [N=32, C=64, H=128, W=128] fp32; two 3x3 convs (stride1 pad1) + train-mode BN + residual.
#define NB 32
#define CH 64
#define HH 128
#define WW 128
#define HW (HH*WW)          // 16384
#define CHW (CH*HW)         // 1048576
#define NCHW (NB*CHW)       // 33554432
#define CNT_PER_CH ((float)(NB*HW))
#define SLOTS 256           // stat partial slots

typedef __attribute__((ext_vector_type(8)))  short short8;
typedef __attribute__((ext_vector_type(16))) float f32x16;

__device__ __forceinline__ unsigned short f2bf(float f) {
  unsigned u = __builtin_bit_cast(unsigned, f);
  u += 0x7fffu + ((u >> 16) & 1u);          // round-to-nearest-even
  return (unsigned short)(u >> 16);
}

// ---------------------------------------------------------------------------
// T1: x NCHW fp32 -> blocked NHWC bf16: xb[n][h][cb=ci/8][w][ci%8]
__global__ __launch_bounds__(256) void t1_pack(const float* __restrict__ x,
                                               unsigned short* __restrict__ xb) {
  __shared__ __align__(16) unsigned short tmp[CH * WW];   // [ci][w] 16KB
  const int bid = blockIdx.x;                 // n*128 + h
  const int tid = threadIdx.x;
  const float* src = x + (size_t)(bid >> 7) * CHW + (size_t)(bid & 127) * WW;
  for (int i = tid; i < 2048; i += 256) {     // 64 ci * 32 float4
    const int ci = i >> 5, wq = i & 31;
    const float4 v = *(const float4*)(src + (size_t)ci * HW + wq * 4);
    unsigned short* d = &tmp[ci * WW + wq * 4];
    d[0] = f2bf(v.x); d[1] = f2bf(v.y); d[2] = f2bf(v.z); d[3] = f2bf(v.w);
  }
  __syncthreads();
  unsigned short* dst = xb + (size_t)bid * 8192;          // 8 cb * 128 w * 8
  for (int i = tid; i < 1024; i += 256) {     // chunks (cb,w)
    const int cb = i >> 7, w = i & 127;
    const unsigned short* s = &tmp[cb * 8 * WW + w];
    uint4 o;
    o.x = (unsigned)s[0]      | ((unsigned)s[WW]     << 16);
    o.y = (unsigned)s[2*WW]   | ((unsigned)s[3*WW]   << 16);
    o.z = (unsigned)s[4*WW]   | ((unsigned)s[5*WW]   << 16);
    o.w = (unsigned)s[6*WW]   | ((unsigned)s[7*WW]   << 16);
    *(uint4*)(dst + ((size_t)cb * WW + w) * 8) = o;
  }
}

// ---------------------------------------------------------------------------
// Weight prepack into MFMA A-fragment order (M=co, K=ci per tap).
// frag f = ((kh*3+kw)*4 + kq)*2 + m ; element [f][lane][r] =
//   w[co=(lane&31)+32m][ci=kq*16+(lane>>5)*8+r][kh][kw]  (* s1[ci] if folding)
// Also emits BN1-bias border tables for conv2 (tabs[9][64]).
__global__ __launch_bounds__(256) void pack_w(const float* __restrict__ w,
                                              const float* __restrict__ s1,
                                              const float* __restrict__ b1,
                                              unsigned short* __restrict__ wpk,
                                              float* __restrict__ tabs) {
  const int tid = threadIdx.x;
  for (int idx = tid; idx < 36864; idx += 256) {
    const int f = idx >> 9, l = (idx >> 3) & 63, r = idx & 7;
    const int m = f & 1, kq = (f >> 1) & 3, t = f >> 3;   // t = kh*3+kw
    const int co = (l & 31) + 32 * m;
    const int ci = kq * 16 + (l >> 5) * 8 + r;
    float v = w[co * 576 + ci * 9 + t];
    if (s1) v *= s1[ci];
    wpk[idx] = f2bf(v);
  }
  if (tabs != nullptr && tid < 64) {
    const int co = tid;
    float tb[9];
    for (int t = 0; t < 9; ++t) {
      float a = 0.f;
      for (int ci = 0; ci < 64; ++ci) a += w[co * 576 + ci * 9 + t] * b1[ci];
      tb[t] = a;
    }
    tabs[0*64+co] = tb[0]+tb[1]+tb[2]+tb[3]+tb[4]+tb[5]+tb[6]+tb[7]+tb[8];
    tabs[1*64+co] = tb[0]+tb[1]+tb[2];   // kh=0 row
    tabs[2*64+co] = tb[6]+tb[7]+tb[8];   // kh=2 row
    tabs[3*64+co] = tb[0]+tb[3]+tb[6];   // kw=0 col
    tabs[4*64+co] = tb[2]+tb[5]+tb[8];   // kw=2 col
    tabs[5*64+co] = tb[0]; tabs[6*64+co] = tb[2];
    tabs[7*64+co] = tb[6]; tabs[8*64+co] = tb[8];
  }
}

// ---------------------------------------------------------------------------
// conv v7 "pure stream": one wave (64 thr) per 32px x 64co tile. No LDS, no
// barriers. B-fragments read directly from blocked-bf16 global (16B/lane,
// coalesced 1KB/instr, L2/L3-served); weights from 72KB L2-hot pack.
// h-edge: skip tap row (uniform). w-edge: clamp addr (med3) + zero fragment.
// 16384 waves/conv; occupancy VGPR-limited only (target 3 waves/SIMD).
template <bool IS2>
__global__ __launch_bounds__(64, 3)
void conv_stream(const unsigned short* __restrict__ inb,
                 const unsigned short* __restrict__ wpack,
                 const float* __restrict__ tabs,
                 const float* __restrict__ resid,       // x fp32 NCHW (IS2)
                 unsigned short* __restrict__ outb,     // conv1 out (blocked bf16)
                 float* __restrict__ outf,              // conv2 out (NCHW fp32)
                 float* __restrict__ psum, float* __restrict__ psq) {
  const int b = blockIdx.x;
  const int vid = ((b & 7) << 11) | (b >> 3);   // XCD-chunked (16384 % 8 == 0)
  const int seg = vid & 3;                      // 32-px segment
  const int h   = (vid >> 2) & 127;
  const int n   = vid >> 9;
  const int lane = threadIdx.x;
  const int half = lane >> 5, lp = lane & 31;
  const int px = (seg << 5) + lp;

  f32x16 acc0 = {}; f32x16 acc1 = {};
  const unsigned short* nbase = inb + (size_t)n * (128 * 8192);

#pragma unroll
  for (int kh = 0; kh < 3; ++kh) {
    const int hr = h + kh - 1;
    if ((unsigned)hr >= 128u) continue;         // wave-uniform skip (zero pad row)
    const unsigned short* rb = nbase + (size_t)hr * 8192;
#pragma unroll
    for (int kw = 0; kw < 3; ++kw) {
      const int pxs = px + kw - 1;
      const bool wok = (unsigned)pxs < 128u;
      const int pxc = pxs < 0 ? 0 : (pxs > 127 ? 127 : pxs);   // med3 clamp
#pragma unroll
      for (int kq = 0; kq < 4; ++kq) {
        const int cb = (kq << 1) + half;
        short8 bf = *(const short8*)(rb + ((size_t)cb << 10) + ((size_t)pxc << 3));
        short8 zz = {};
        if (!wok) bf = zz;                      // zero the 2 edge lanes
        const int f = (((kh * 3 + kw) << 2) + kq) << 1;
        const short8 w0 = *(const short8*)(wpack + ((size_t)f << 9) + ((size_t)lane << 3));
        const short8 w1 = *(const short8*)(wpack + ((size_t)(f + 1) << 9) + ((size_t)lane << 3));
        acc0 = __builtin_amdgcn_mfma_f32_32x32x16_bf16(w0, bf, acc0, 0, 0, 0);
        acc1 = __builtin_amdgcn_mfma_f32_32x32x16_bf16(w1, bf, acc1, 0, 0, 0);
      }
    }
  }

  // ---- epilogue ----
  if (!IS2) {
    unsigned short* dst = outb + (size_t)(n * 128 + h) * 8192;
#pragma unroll
    for (int m = 0; m < 2; ++m) {
      const f32x16& a = m ? acc1 : acc0;
#pragma unroll
      for (int rq = 0; rq < 4; ++rq) {
        uint2 pk;
        pk.x = (unsigned)f2bf(a[rq*4+0]) | ((unsigned)f2bf(a[rq*4+1]) << 16);
        pk.y = (unsigned)f2bf(a[rq*4+2]) | ((unsigned)f2bf(a[rq*4+3]) << 16);
        *(uint2*)(dst + (((size_t)(rq + (m << 2))) << 10) + ((size_t)px << 3) + (half << 2)) = pk;
      }
    }
  } else {
    const bool bh0 = (h == 0), bh1 = (h == 127);
    const bool bw0 = (px == 0), bw1 = (px == 127);
#pragma unroll
    for (int m = 0; m < 2; ++m) {
      f32x16& a = m ? acc1 : acc0;
#pragma unroll
      for (int r = 0; r < 16; ++r) {
        const int co = (r & 3) + ((r >> 2) << 3) + (half << 2) + (m << 5);
        float tb = tabs[co];
        if (bh0) tb -= tabs[64 + co];
        if (bh1) tb -= tabs[128 + co];
        if (bw0) tb -= tabs[192 + co];
        if (bw1) tb -= tabs[256 + co];
        if (bh0 && bw0) tb += tabs[320 + co];
        if (bh0 && bw1) tb += tabs[384 + co];
        if (bh1 && bw0) tb += tabs[448 + co];
        if (bh1 && bw1) tb += tabs[512 + co];
        const size_t oi = (((size_t)(n * 64 + co)) * 128 + h) * 128 + px;
        const float v = a[r] + tb + resid[oi];
        outf[oi] = v;
        a[r] = v;
      }
    }
  }

  // ---- per-channel batch stats: shuffle tree over the 32 px lanes ----
  const int slot = vid & (SLOTS - 1);
#pragma unroll
  for (int m = 0; m < 2; ++m) {
    const f32x16& a = m ? acc1 : acc0;
#pragma unroll
    for (int r = 0; r < 16; ++r) {
      float s = a[r], q = a[r] * a[r];
      s += __shfl_xor(s, 1);  q += __shfl_xor(q, 1);
      s += __shfl_xor(s, 2);  q += __shfl_xor(q, 2);
      s += __shfl_xor(s, 4);  q += __shfl_xor(q, 4);
      s += __shfl_xor(s, 8);  q += __shfl_xor(q, 8);
      s += __shfl_xor(s, 16); q += __shfl_xor(q, 16);
      if (lp == 0) {
        const int co = (r & 3) + ((r >> 2) << 3) + (half << 2) + (m << 5);
        atomicAdd(&psum[slot * 64 + co], s);
        atomicAdd(&psq [slot * 64 + co], q);
      }
    }
  }
}

// ---------------------------------------------------------------------------
// Reduce SLOTS per-slot partials -> fused scale/bias.
__global__ __launch_bounds__(256)
void finalize_bn(const float* __restrict__ psum, const float* __restrict__ psq,
                 const float* __restrict__ gamma, const float* __restrict__ beta,
                 float* __restrict__ scale, float* __restrict__ bias) {
  __shared__ float ls[4][64], lq[4][64];
  const int c = threadIdx.x & 63, sg = threadIdx.x >> 6;
  float s = 0.f, q = 0.f;
  for (int i = sg * (SLOTS / 4); i < (sg + 1) * (SLOTS / 4); ++i) {
    s += psum[(size_t)i * 64 + c];
    q += psq[(size_t)i * 64 + c];
  }
  ls[sg][c] = s; lq[sg][c] = q;
  __syncthreads();
  if (threadIdx.x < 64) {
    s = ls[0][c] + ls[1][c] + ls[2][c] + ls[3][c];
    q = lq[0][c] + lq[1][c] + lq[2][c] + lq[3][c];
    const float mean = s * (1.0f / CNT_PER_CH);
    const float var  = q * (1.0f / CNT_PER_CH) - mean * mean;
    const float inv  = rsqrtf(var + 1e-5f);
    const float sc   = inv * gamma[c];
    scale[c] = sc;
    bias[c]  = beta[c] - mean * sc;
  }
}

// In-place BN2 apply on d_out, float4-vectorized.
__global__ __launch_bounds__(256)
void apply_bn_k(float* __restrict__ out,
                const float* __restrict__ scale, const float* __restrict__ bias) {
  __shared__ float sc[CH], bs[CH];
  if (threadIdx.x < CH) { sc[threadIdx.x] = scale[threadIdx.x]; bs[threadIdx.x] = bias[threadIdx.x]; }
  __syncthreads();
  const size_t total4 = NCHW / 4;
  for (size_t i = (size_t)blockIdx.x * blockDim.x + threadIdx.x; i < total4;
       i += (size_t)gridDim.x * blockDim.x) {
    float4 v = reinterpret_cast<float4*>(out)[i];
    const int c = (int)(((i * 4) >> 14) & 63);
    const float s = sc[c], b = bs[c];
    v.x = fmaf(v.x, s, b);
    v.y = fmaf(v.y, s, b);
    v.z = fmaf(v.z, s, b);
    v.w = fmaf(v.w, s, b);
    reinterpret_cast<float4*>(out)[i] = v;
  }
}

// ---------------------------------------------------------------------------
extern "C" void kernel_launch(void* const* d_in, const int* in_sizes, int n_in,
                              void* d_out, int out_size, void* d_ws, size_t ws_size,
                              hipStream_t stream) {
  const float* x  = (const float*)d_in[0];
  const float* w1 = (const float*)d_in[1];
  const float* w2 = (const float*)d_in[2];
  const float* g1 = (const float*)d_in[3];
  const float* b1 = (const float*)d_in[4];
  const float* g2 = (const float*)d_in[5];
  const float* b2 = (const float*)d_in[6];
  float* out = (float*)d_out;
  char* ws = (char*)d_ws;

  // ws: [XB bf16 64MiB][Y1B bf16 64MiB] (peak usage exactly 128 MiB, as proven)
  unsigned short* XB  = (unsigned short*)ws;
  unsigned short* Y1B = (unsigned short*)(ws + 67108864);
  // overlays in XB region (dead after conv1):
  unsigned short* W2P = (unsigned short*)ws;          // 73728 B
  float* TABS = (float*)(ws + 73728);                 // 2304 B
  float* SC1  = (float*)(ws + 76032);
  float* BS1  = (float*)(ws + 76288);
  float* SC2  = (float*)(ws + 76544);
  float* BS2  = (float*)(ws + 76800);
  float* P2S  = (float*)(ws + 131072);                // 64 KB (SLOTS*64 f32)
  float* P2Q  = (float*)(ws + 131072 + 65536);        // 64 KB
  // overlays in d_out (free until conv2 writes it):
  char* ob = (char*)d_out;
  unsigned short* W1P = (unsigned short*)ob;          // 73728 B
  float* P1S = (float*)(ob + 73728);                  // 64 KB
  float* P1Q = (float*)(ob + 73728 + 65536);          // 64 KB

  pack_w<<<1, 256, 0, stream>>>(w1, nullptr, nullptr, W1P, nullptr);
  hipMemsetAsync(ob + 73728, 0, 131072, stream);                // zero P1
  t1_pack<<<4096, 256, 0, stream>>>(x, XB);
  conv_stream<false><<<16384, 64, 0, stream>>>(XB, W1P, nullptr, nullptr,
                                               Y1B, nullptr, P1S, P1Q);
  finalize_bn<<<1, 256, 0, stream>>>(P1S, P1Q, g1, b1, SC1, BS1);
  hipMemsetAsync(ws + 131072, 0, 131072, stream);               // zero P2 (XB dead)
  pack_w<<<1, 256, 0, stream>>>(w2, SC1, BS1, W2P, TABS);
  conv_stream<true><<<16384, 64, 0, stream>>>(Y1B, W2P, TABS, x,
                                              nullptr, out, P2S, P2Q);
  finalize_bn<<<1, 256, 0, stream>>>(P2S, P2Q, g2, b2, SC2, BS2);
  apply_bn_k<<<2048, 256, 0, stream>>>(out, SC2, BS2);
}